// Round 1
// baseline (685.828 us; speedup 1.0000x reference)
//
#include <hip/hip_runtime.h>

// ---------------------------------------------------------------------------
// CausalSelfAttention fused block, MI355X (gfx950)
// x[1,4096,1024] f32, W_qkv[3072,1024] f32, W_o[1024,1024] f32 -> out[1,4096,1024] f32
// Pipeline: cvt->bf16, GEMM1 (qkv), RoPE+reshape, flash attention, GEMM2.
// All MFMA 16x16x32 bf16, fp32 accum. Round 0: correctness-first.
// ---------------------------------------------------------------------------

typedef __attribute__((ext_vector_type(8))) short short8;
typedef __attribute__((ext_vector_type(4))) float f32x4;
typedef __attribute__((ext_vector_type(4))) float float4v;
typedef __attribute__((ext_vector_type(4))) unsigned short ushort4v;

#define S_LEN 4096
#define DMODEL 1024
#define NHEADS 16
#define DKH 64

__device__ __forceinline__ unsigned short f2bf(float f) {
  unsigned u = __builtin_bit_cast(unsigned, f);
  u += 0x7FFFu + ((u >> 16) & 1u);   // round-to-nearest-even
  return (unsigned short)(u >> 16);
}
__device__ __forceinline__ float bf2f(unsigned short h) {
  return __builtin_bit_cast(float, ((unsigned)h) << 16);
}

// ---------------------------------------------------------------------------
// fp32 -> bf16 conversion, vectorized (float4 in, 4x bf16 out)
// ---------------------------------------------------------------------------
__global__ void cvt_bf16_kernel(const float* __restrict__ src,
                                unsigned short* __restrict__ dst, int n4) {
  int i = blockIdx.x * blockDim.x + threadIdx.x;
  if (i >= n4) return;
  float4v v = reinterpret_cast<const float4v*>(src)[i];
  ushort4v o;
  o[0] = f2bf(v[0]); o[1] = f2bf(v[1]); o[2] = f2bf(v[2]); o[3] = f2bf(v[3]);
  reinterpret_cast<ushort4v*>(dst)[i] = o;
}

// ---------------------------------------------------------------------------
// GEMM: C[M,N] = A[M,K] * B[N,K]^T   (A,B bf16 row-major contiguous along K)
// Block: 256 thr = 4 waves (2x2), tile 64(M) x 128(N). Wave: 32x64 (2x4 frags).
// No LDS (L2-reliant) -- round-0 simplicity.
// ---------------------------------------------------------------------------
template<bool OUT_BF16>
__global__ __launch_bounds__(256) void gemm_bt(const unsigned short* __restrict__ A,
                                               const unsigned short* __restrict__ B,
                                               void* __restrict__ Cp,
                                               int M, int N, int K) {
  const int l  = threadIdx.x & 63;
  const int w  = threadIdx.x >> 6;
  const int wr = w >> 1, wc = w & 1;
  const int bm = blockIdx.y * 64, bn = blockIdx.x * 128;
  const int lr = l & 15, lk = (l >> 4) * 8;

  f32x4 acc[2][4] = {};

  const unsigned short* ap = A + (size_t)(bm + wr * 32 + lr) * K + lk;
  const unsigned short* bp = B + (size_t)(bn + wc * 64 + lr) * K + lk;
  const size_t aK = (size_t)16 * K;

  for (int k0 = 0; k0 < K; k0 += 32) {
    short8 a0 = *(const short8*)(ap + k0);
    short8 a1 = *(const short8*)(ap + aK + k0);
    short8 b0 = *(const short8*)(bp + k0);
    short8 b1 = *(const short8*)(bp + aK + k0);
    short8 b2 = *(const short8*)(bp + 2 * aK + k0);
    short8 b3 = *(const short8*)(bp + 3 * aK + k0);
    acc[0][0] = __builtin_amdgcn_mfma_f32_16x16x32_bf16(a0, b0, acc[0][0], 0, 0, 0);
    acc[0][1] = __builtin_amdgcn_mfma_f32_16x16x32_bf16(a0, b1, acc[0][1], 0, 0, 0);
    acc[0][2] = __builtin_amdgcn_mfma_f32_16x16x32_bf16(a0, b2, acc[0][2], 0, 0, 0);
    acc[0][3] = __builtin_amdgcn_mfma_f32_16x16x32_bf16(a0, b3, acc[0][3], 0, 0, 0);
    acc[1][0] = __builtin_amdgcn_mfma_f32_16x16x32_bf16(a1, b0, acc[1][0], 0, 0, 0);
    acc[1][1] = __builtin_amdgcn_mfma_f32_16x16x32_bf16(a1, b1, acc[1][1], 0, 0, 0);
    acc[1][2] = __builtin_amdgcn_mfma_f32_16x16x32_bf16(a1, b2, acc[1][2], 0, 0, 0);
    acc[1][3] = __builtin_amdgcn_mfma_f32_16x16x32_bf16(a1, b3, acc[1][3], 0, 0, 0);
  }

  const int row0 = bm + wr * 32 + (l >> 4) * 4;
  const int col0 = bn + wc * 64 + lr;
#pragma unroll
  for (int mi = 0; mi < 2; mi++)
#pragma unroll
    for (int ni = 0; ni < 4; ni++)
#pragma unroll
      for (int j = 0; j < 4; j++) {
        size_t idx = (size_t)(row0 + mi * 16 + j) * N + (col0 + ni * 16);
        if (OUT_BF16) ((unsigned short*)Cp)[idx] = f2bf(acc[mi][ni][j]);
        else          ((float*)Cp)[idx]          = acc[mi][ni][j];
      }
}

// ---------------------------------------------------------------------------
// RoPE (rotate_half) on Q,K + head reshape. V is transposed to [H][64][S]
// so PV B-fragments are contiguous 16B loads.
// ---------------------------------------------------------------------------
__global__ void rope_split_kernel(const unsigned short* __restrict__ qkv,
                                  unsigned short* __restrict__ Qr,
                                  unsigned short* __restrict__ Kr,
                                  unsigned short* __restrict__ Vt) {
  int gid = blockIdx.x * blockDim.x + threadIdx.x;  // 0 .. 4M-1
  int s = gid >> 10;
  int e = gid & 1023;
  int h = e >> 6, d = e & 63;
  size_t base = (size_t)s * 3072;

  float q = bf2f(qkv[base + e]);
  float k = bf2f(qkv[base + 1024 + e]);

  int i = d & 31;
  // inv_freq = 10000^(-2i/64)
  float inv = expf(-(float)(2 * i) * (9.2103403719761836f / 64.0f));
  float ang = (float)s * inv;
  float sn, cs;
  sincosf(ang, &sn, &cs);

  int ep = (d < 32) ? (e + 32) : (e - 32);
  float qp = bf2f(qkv[base + ep]);
  float kp = bf2f(qkv[base + 1024 + ep]);

  float qo, ko;
  if (d < 32) { qo = q * cs - qp * sn; ko = k * cs - kp * sn; }
  else        { qo = q * cs + qp * sn; ko = k * cs + kp * sn; }

  size_t oidx = ((size_t)h * S_LEN + s) * DKH + d;
  Qr[oidx] = f2bf(qo);
  Kr[oidx] = f2bf(ko);
  Vt[((size_t)h * DKH + d) * S_LEN + s] = qkv[base + 2048 + e];  // bit passthrough
}

// ---------------------------------------------------------------------------
// Flash attention, causal. 1 wave/block, 16 q-rows, 32-key chunks.
// QK^T: 4 MFMAs/chunk; online softmax via 16-lane butterflies; P->LDS
// transpose (padded stride 40); PV: 4 MFMAs/chunk from transposed V.
// ---------------------------------------------------------------------------
__global__ __launch_bounds__(64) void flash_attn_kernel(const unsigned short* __restrict__ Qr,
                                                        const unsigned short* __restrict__ Kr,
                                                        const unsigned short* __restrict__ Vt,
                                                        unsigned short* __restrict__ O) {
  __shared__ __align__(16) unsigned short plds[16][40];
  const int l  = threadIdx.x;
  const int h  = blockIdx.y;
  const int q0 = blockIdx.x * 16;
  const int lr = l & 15, lg = l >> 4;

  const unsigned short* Qh = Qr + (size_t)h * S_LEN * DKH;
  const unsigned short* Kh = Kr + (size_t)h * S_LEN * DKH;
  const unsigned short* Vh = Vt + (size_t)h * DKH * S_LEN;

  short8 aq0 = *(const short8*)(Qh + (q0 + lr) * 64 + lg * 8);
  short8 aq1 = *(const short8*)(Qh + (q0 + lr) * 64 + 32 + lg * 8);

  f32x4 acc[4] = {};
  float mrow[4] = {-1e30f, -1e30f, -1e30f, -1e30f};
  float lrow[4] = {};

  const int kvmax = ((q0 + 15) >> 5) << 5;  // kvmax <= q0 always
  for (int kv0 = 0; kv0 <= kvmax; kv0 += 32) {
    short8 bk00 = *(const short8*)(Kh + (kv0 + lr) * 64 + lg * 8);
    short8 bk01 = *(const short8*)(Kh + (kv0 + lr) * 64 + 32 + lg * 8);
    short8 bk10 = *(const short8*)(Kh + (kv0 + 16 + lr) * 64 + lg * 8);
    short8 bk11 = *(const short8*)(Kh + (kv0 + 16 + lr) * 64 + 32 + lg * 8);

    f32x4 s0 = {}, s1 = {};
    s0 = __builtin_amdgcn_mfma_f32_16x16x32_bf16(aq0, bk00, s0, 0, 0, 0);
    s0 = __builtin_amdgcn_mfma_f32_16x16x32_bf16(aq1, bk01, s0, 0, 0, 0);
    s1 = __builtin_amdgcn_mfma_f32_16x16x32_bf16(aq0, bk10, s1, 0, 0, 0);
    s1 = __builtin_amdgcn_mfma_f32_16x16x32_bf16(aq1, bk11, s1, 0, 0, 0);

    float p0[4], p1[4], scl[4];
    const bool needmask = (kv0 + 31 > q0);
#pragma unroll
    for (int j = 0; j < 4; j++) {
      float v0 = s0[j] * 0.125f;   // 1/sqrt(64)
      float v1 = s1[j] * 0.125f;
      if (needmask) {
        int row = q0 + lg * 4 + j;
        if (kv0 + lr > row)      v0 = -1e30f;
        if (kv0 + 16 + lr > row) v1 = -1e30f;
      }
      p0[j] = v0; p1[j] = v1;
    }
#pragma unroll
    for (int j = 0; j < 4; j++) {
      float rm = fmaxf(p0[j], p1[j]);
      rm = fmaxf(rm, __shfl_xor(rm, 1));
      rm = fmaxf(rm, __shfl_xor(rm, 2));
      rm = fmaxf(rm, __shfl_xor(rm, 4));
      rm = fmaxf(rm, __shfl_xor(rm, 8));
      float mn = fmaxf(mrow[j], rm);
      scl[j] = __expf(mrow[j] - mn);
      mrow[j] = mn;
      float e0 = __expf(p0[j] - mn);
      float e1 = __expf(p1[j] - mn);
      p0[j] = e0; p1[j] = e1;
      float rs = e0 + e1;
      rs += __shfl_xor(rs, 1);
      rs += __shfl_xor(rs, 2);
      rs += __shfl_xor(rs, 4);
      rs += __shfl_xor(rs, 8);
      lrow[j] = lrow[j] * scl[j] + rs;
    }
#pragma unroll
    for (int db = 0; db < 4; db++)
#pragma unroll
      for (int j = 0; j < 4; j++) acc[db][j] *= scl[j];

#pragma unroll
    for (int j = 0; j < 4; j++) {
      plds[lg * 4 + j][lr]      = f2bf(p0[j]);
      plds[lg * 4 + j][16 + lr] = f2bf(p1[j]);
    }
    __syncthreads();
    short8 pa = *(const short8*)&plds[lr][lg * 8];
#pragma unroll
    for (int db = 0; db < 4; db++) {
      short8 bv = *(const short8*)(Vh + (size_t)(db * 16 + lr) * S_LEN + kv0 + lg * 8);
      acc[db] = __builtin_amdgcn_mfma_f32_16x16x32_bf16(pa, bv, acc[db], 0, 0, 0);
    }
    __syncthreads();
  }

#pragma unroll
  for (int db = 0; db < 4; db++)
#pragma unroll
    for (int j = 0; j < 4; j++) {
      float val = acc[db][j] / lrow[j];
      O[(size_t)(q0 + lg * 4 + j) * DMODEL + h * 64 + db * 16 + lr] = f2bf(val);
    }
}

// ---------------------------------------------------------------------------
// launch
// ---------------------------------------------------------------------------
extern "C" void kernel_launch(void* const* d_in, const int* in_sizes, int n_in,
                              void* d_out, int out_size, void* d_ws, size_t ws_size,
                              hipStream_t stream) {
  (void)in_sizes; (void)n_in; (void)out_size; (void)ws_size;
  const float* x    = (const float*)d_in[0];   // [4096,1024]
  const float* Wqkv = (const float*)d_in[1];   // [3072,1024]
  const float* Wo   = (const float*)d_in[2];   // [1024,1024]
  float* out = (float*)d_out;                  // [4096,1024]

  char* ws = (char*)d_ws;
  const size_t MB = 1u << 20;
  unsigned short* x_bf    = (unsigned short*)(ws + 0 * MB);    //  8 MB
  unsigned short* wqkv_bf = (unsigned short*)(ws + 8 * MB);    //  6 MB
  unsigned short* wo_bf   = (unsigned short*)(ws + 14 * MB);   //  2 MB
  unsigned short* qkv_bf  = (unsigned short*)(ws + 16 * MB);   // 24 MB
  unsigned short* Qr      = (unsigned short*)(ws + 40 * MB);   //  8 MB
  unsigned short* Kr      = (unsigned short*)(ws + 48 * MB);   //  8 MB
  unsigned short* Vt      = (unsigned short*)(ws + 56 * MB);   //  8 MB
  unsigned short* Obf     = (unsigned short*)(ws + 64 * MB);   //  8 MB  (end: 72 MB)

  const int n_x = 4096 * 1024, n_wqkv = 3072 * 1024, n_wo = 1024 * 1024;
  cvt_bf16_kernel<<<(n_x / 4 + 255) / 256, 256, 0, stream>>>(x, x_bf, n_x / 4);
  cvt_bf16_kernel<<<(n_wqkv / 4 + 255) / 256, 256, 0, stream>>>(Wqkv, wqkv_bf, n_wqkv / 4);
  cvt_bf16_kernel<<<(n_wo / 4 + 255) / 256, 256, 0, stream>>>(Wo, wo_bf, n_wo / 4);

  // qkv[s,e] = sum_d x[s,d] * Wqkv[e,d]
  gemm_bt<true><<<dim3(3072 / 128, 4096 / 64), 256, 0, stream>>>(x_bf, wqkv_bf, qkv_bf,
                                                                 4096, 3072, 1024);
  rope_split_kernel<<<(4096 * 1024) / 256, 256, 0, stream>>>(qkv_bf, Qr, Kr, Vt);

  flash_attn_kernel<<<dim3(S_LEN / 16, NHEADS), 64, 0, stream>>>(Qr, Kr, Vt, Obf);

  // out[s,e'] = sum_e O[s,e] * Wo[e',e]
  gemm_bt<false><<<dim3(1024 / 128, 4096 / 64), 256, 0, stream>>>(Obf, wo_bf, out,
                                                                  4096, 1024, 1024);
}

// Round 3
// 379.345 us; speedup vs baseline: 1.8079x; 1.8079x over previous
//
#include <hip/hip_runtime.h>

// ---------------------------------------------------------------------------
// CausalSelfAttention fused block, MI355X (gfx950)
// Round 2: round-1 kernel with the __exp2f -> exp2f compile fix.
// Swapped-QK^T 32x32 flash attention (lane-local softmax), exp2-domain,
// defer-max, XCD-pinned heads. GEMMs unchanged from round 0.
// ---------------------------------------------------------------------------

typedef __attribute__((ext_vector_type(8)))  short  short8;
typedef __attribute__((ext_vector_type(4)))  float  f32x4;
typedef __attribute__((ext_vector_type(16))) float  f32x16;
typedef __attribute__((ext_vector_type(4)))  float  float4v;
typedef __attribute__((ext_vector_type(4)))  unsigned short ushort4v;
typedef __attribute__((ext_vector_type(4)))  unsigned int   uint4v;

#define S_LEN 4096
#define DMODEL 1024
#define NHEADS 16
#define DKH 64

// 0.125 * log2(e): folds 1/sqrt(64) and the exp->exp2 conversion into Q.
#define QSCALE 0.18033688011112042f

__device__ __forceinline__ unsigned short f2bf(float f) {
  unsigned u = __builtin_bit_cast(unsigned, f);
  u += 0x7FFFu + ((u >> 16) & 1u);   // round-to-nearest-even
  return (unsigned short)(u >> 16);
}
__device__ __forceinline__ float bf2f(unsigned short h) {
  return __builtin_bit_cast(float, ((unsigned)h) << 16);
}

// ---------------------------------------------------------------------------
// fp32 -> bf16 conversion
// ---------------------------------------------------------------------------
__global__ void cvt_bf16_kernel(const float* __restrict__ src,
                                unsigned short* __restrict__ dst, int n4) {
  int i = blockIdx.x * blockDim.x + threadIdx.x;
  if (i >= n4) return;
  float4v v = reinterpret_cast<const float4v*>(src)[i];
  ushort4v o;
  o[0] = f2bf(v[0]); o[1] = f2bf(v[1]); o[2] = f2bf(v[2]); o[3] = f2bf(v[3]);
  reinterpret_cast<ushort4v*>(dst)[i] = o;
}

// ---------------------------------------------------------------------------
// GEMM: C[M,N] = A[M,K] * B[N,K]^T
// ---------------------------------------------------------------------------
template<bool OUT_BF16>
__global__ __launch_bounds__(256) void gemm_bt(const unsigned short* __restrict__ A,
                                               const unsigned short* __restrict__ B,
                                               void* __restrict__ Cp,
                                               int M, int N, int K) {
  const int l  = threadIdx.x & 63;
  const int w  = threadIdx.x >> 6;
  const int wr = w >> 1, wc = w & 1;
  const int bm = blockIdx.y * 64, bn = blockIdx.x * 128;
  const int lr = l & 15, lk = (l >> 4) * 8;

  f32x4 acc[2][4] = {};

  const unsigned short* ap = A + (size_t)(bm + wr * 32 + lr) * K + lk;
  const unsigned short* bp = B + (size_t)(bn + wc * 64 + lr) * K + lk;
  const size_t aK = (size_t)16 * K;

  for (int k0 = 0; k0 < K; k0 += 32) {
    short8 a0 = *(const short8*)(ap + k0);
    short8 a1 = *(const short8*)(ap + aK + k0);
    short8 b0 = *(const short8*)(bp + k0);
    short8 b1 = *(const short8*)(bp + aK + k0);
    short8 b2 = *(const short8*)(bp + 2 * aK + k0);
    short8 b3 = *(const short8*)(bp + 3 * aK + k0);
    acc[0][0] = __builtin_amdgcn_mfma_f32_16x16x32_bf16(a0, b0, acc[0][0], 0, 0, 0);
    acc[0][1] = __builtin_amdgcn_mfma_f32_16x16x32_bf16(a0, b1, acc[0][1], 0, 0, 0);
    acc[0][2] = __builtin_amdgcn_mfma_f32_16x16x32_bf16(a0, b2, acc[0][2], 0, 0, 0);
    acc[0][3] = __builtin_amdgcn_mfma_f32_16x16x32_bf16(a0, b3, acc[0][3], 0, 0, 0);
    acc[1][0] = __builtin_amdgcn_mfma_f32_16x16x32_bf16(a1, b0, acc[1][0], 0, 0, 0);
    acc[1][1] = __builtin_amdgcn_mfma_f32_16x16x32_bf16(a1, b1, acc[1][1], 0, 0, 0);
    acc[1][2] = __builtin_amdgcn_mfma_f32_16x16x32_bf16(a1, b2, acc[1][2], 0, 0, 0);
    acc[1][3] = __builtin_amdgcn_mfma_f32_16x16x32_bf16(a1, b3, acc[1][3], 0, 0, 0);
  }

  const int row0 = bm + wr * 32 + (l >> 4) * 4;
  const int col0 = bn + wc * 64 + lr;
#pragma unroll
  for (int mi = 0; mi < 2; mi++)
#pragma unroll
    for (int ni = 0; ni < 4; ni++)
#pragma unroll
      for (int j = 0; j < 4; j++) {
        size_t idx = (size_t)(row0 + mi * 16 + j) * N + (col0 + ni * 16);
        if (OUT_BF16) ((unsigned short*)Cp)[idx] = f2bf(acc[mi][ni][j]);
        else          ((float*)Cp)[idx]          = acc[mi][ni][j];
      }
}

// ---------------------------------------------------------------------------
// RoPE + head reshape. Q pre-scaled by 0.125*log2e. V transposed to [H][64][S].
// ---------------------------------------------------------------------------
__global__ void rope_split_kernel(const unsigned short* __restrict__ qkv,
                                  unsigned short* __restrict__ Qr,
                                  unsigned short* __restrict__ Kr,
                                  unsigned short* __restrict__ Vt) {
  int gid = blockIdx.x * blockDim.x + threadIdx.x;  // 0 .. 4M-1
  int s = gid >> 10;
  int e = gid & 1023;
  int h = e >> 6, d = e & 63;
  size_t base = (size_t)s * 3072;

  float q = bf2f(qkv[base + e]);
  float k = bf2f(qkv[base + 1024 + e]);

  int i = d & 31;
  float inv = expf(-(float)(2 * i) * (9.2103403719761836f / 64.0f));
  float ang = (float)s * inv;
  float sn, cs;
  sincosf(ang, &sn, &cs);

  int ep = (d < 32) ? (e + 32) : (e - 32);
  float qp = bf2f(qkv[base + ep]);
  float kp = bf2f(qkv[base + 1024 + ep]);

  float qo, ko;
  if (d < 32) { qo = q * cs - qp * sn; ko = k * cs - kp * sn; }
  else        { qo = q * cs + qp * sn; ko = k * cs + kp * sn; }

  size_t oidx = ((size_t)h * S_LEN + s) * DKH + d;
  Qr[oidx] = f2bf(qo * QSCALE);
  Kr[oidx] = f2bf(ko);
  Vt[((size_t)h * DKH + d) * S_LEN + s] = qkv[base + 2048 + e];
}

// ---------------------------------------------------------------------------
// Flash attention, swapped-QK^T 32x32x16 structure.
// 1 wave/block, QBLK=32 q-rows/wave, KVBLK=32.
//  S^T = mfma(K, Q): lane (hi,r) holds S[key=kv0+koff(reg,hi)][q=q0+r]
//    koff(reg,hi) = (reg&3) + 8*(reg>>2) + 4*hi   -- m74/m101 C/D layout
//  Softmax state (m, l) lane-local.  O^T = mfma(V^T, P^T): col=q lane-local.
// ---------------------------------------------------------------------------
__global__ __launch_bounds__(64) void flash_attn_kernel(const unsigned short* __restrict__ Qr,
                                                        const unsigned short* __restrict__ Kr,
                                                        const unsigned short* __restrict__ Vt,
                                                        unsigned short* __restrict__ O) {
  __shared__ __align__(16) unsigned short olds[32][72];

  const int l  = threadIdx.x;
  const int r  = l & 31;
  const int hi = l >> 5;

  // XCD-pinned head mapping + longest-tile-first dispatch.
  const int bx    = blockIdx.x;          // 0..2047
  const int xcd   = bx & 7;
  const int j     = bx >> 3;             // 0..255
  const int h     = xcd * 2 + (j & 1);   // 2 heads per XCD -> K/V L2-resident
  const int qtile = 127 - (j >> 1);      // longest first
  const int q0    = qtile * 32;

  const unsigned short* Qh = Qr + (size_t)h * S_LEN * DKH;
  const unsigned short* Kh = Kr + (size_t)h * S_LEN * DKH;
  const unsigned short* Vh = Vt + (size_t)h * DKH * S_LEN;

  // Q B-fragments (col=q, k=d-chunk), pre-scaled by QSCALE in rope.
  short8 qf[4];
  {
    const unsigned short* qb = Qh + (size_t)(q0 + r) * 64 + hi * 8;
#pragma unroll
    for (int dc = 0; dc < 4; dc++) qf[dc] = *(const short8*)(qb + dc * 16);
  }

  f32x16 acc0 = {}, acc1 = {};     // O^T tiles: d 0..31 / 32..63, col=q
  float m = -1e30f, lsum = 0.0f;

  // preload K chunk 0 (A-frag: row=key, k=d)
  short8 kf[4];
  {
    const unsigned short* kb = Kh + (size_t)r * 64 + hi * 8;
#pragma unroll
    for (int dc = 0; dc < 4; dc++) kf[dc] = *(const short8*)(kb + dc * 16);
  }

  for (int c = 0; c <= qtile; c++) {
    const int kv0 = c << 5;

    // V A-frags issued early (consumed after softmax): row=d, k=key
    short8 vf[4];
    {
      const unsigned short* vb = Vh + (size_t)r * S_LEN + kv0 + hi * 8;
#pragma unroll
      for (int dt = 0; dt < 2; dt++)
#pragma unroll
        for (int kc = 0; kc < 2; kc++)
          vf[dt * 2 + kc] = *(const short8*)(vb + (size_t)dt * 32 * S_LEN + kc * 16);
    }

    // S^T = K . Q^T  (d accumulated over 4 chunks of 16)
    f32x16 st = {};
    st = __builtin_amdgcn_mfma_f32_32x32x16_bf16(kf[0], qf[0], st, 0, 0, 0);
    st = __builtin_amdgcn_mfma_f32_32x32x16_bf16(kf[1], qf[1], st, 0, 0, 0);
    st = __builtin_amdgcn_mfma_f32_32x32x16_bf16(kf[2], qf[2], st, 0, 0, 0);
    st = __builtin_amdgcn_mfma_f32_32x32x16_bf16(kf[3], qf[3], st, 0, 0, 0);

    // prefetch next K chunk under the softmax
    short8 kfn[4];
    if (c < qtile) {
      const unsigned short* kb = Kh + (size_t)(kv0 + 32 + r) * 64 + hi * 8;
#pragma unroll
      for (int dc = 0; dc < 4; dc++) kfn[dc] = *(const short8*)(kb + dc * 16);
    }

    // causal mask: only the diagonal chunk
    if (c == qtile) {
#pragma unroll
      for (int reg = 0; reg < 16; reg++) {
        const int koff = (reg & 3) + 8 * (reg >> 2) + 4 * hi;
        if (koff > r) st[reg] = -1e30f;
      }
    }

    // --- lane-local online softmax (exp2 domain) ---
    float t[8];
#pragma unroll
    for (int i = 0; i < 8; i++) t[i] = fmaxf(st[2 * i], st[2 * i + 1]);
#pragma unroll
    for (int i = 0; i < 4; i++) t[i] = fmaxf(t[i], t[i + 4]);
    float pm = fmaxf(fmaxf(t[0], t[2]), fmaxf(t[1], t[3]));
    pm = fmaxf(pm, __shfl_xor(pm, 32));

    // defer-max (T13, THR=8): skip O-rescale while chunk max stays within 2^8
    if (!__all(pm <= m + 8.0f)) {
      float mn  = fmaxf(m, pm);
      float scl = exp2f(m - mn);
      m = mn;
      lsum *= scl;
#pragma unroll
      for (int reg = 0; reg < 16; reg++) { acc0[reg] *= scl; acc1[reg] *= scl; }
    }

    float p[16];
#pragma unroll
    for (int reg = 0; reg < 16; reg++) p[reg] = exp2f(st[reg] - m);

    float s2[8];
#pragma unroll
    for (int i = 0; i < 8; i++) s2[i] = p[2 * i] + p[2 * i + 1];
#pragma unroll
    for (int i = 0; i < 4; i++) s2[i] = s2[i] + s2[i + 4];
    float rs = (s2[0] + s2[2]) + (s2[1] + s2[3]);
    rs += __shfl_xor(rs, 32);
    lsum += rs;

    // --- pack P to bf16 words (v_cvt_pk) and build PV B-fragments ---
    unsigned w[8];
#pragma unroll
    for (int i = 0; i < 8; i++) {
      asm("v_cvt_pk_bf16_f32 %0, %1, %2" : "=v"(w[i]) : "v"(p[2 * i]), "v"(p[2 * i + 1]));
    }
    unsigned pw[8];
#pragma unroll
    for (int i = 0; i < 8; i++) pw[i] = __shfl_xor(w[i], 32);

    // B-frag keys per word jw: hi=0 -> {2jw,2jw+1}; hi=1 -> {8+2jw,9+2jw} (+16 for kc=1)
    uint4v u0, u1;
    u0[0] = hi ? pw[2] : w[0];
    u0[1] = hi ? pw[3] : w[1];
    u0[2] = hi ? w[2]  : pw[0];
    u0[3] = hi ? w[3]  : pw[1];
    u1[0] = hi ? pw[6] : w[4];
    u1[1] = hi ? pw[7] : w[5];
    u1[2] = hi ? w[6]  : pw[4];
    u1[3] = hi ? w[7]  : pw[5];
    short8 pa0 = __builtin_bit_cast(short8, u0);   // keys kv0+0..15
    short8 pa1 = __builtin_bit_cast(short8, u1);   // keys kv0+16..31

    // O^T += V^T . P
    acc0 = __builtin_amdgcn_mfma_f32_32x32x16_bf16(vf[0], pa0, acc0, 0, 0, 0);
    acc0 = __builtin_amdgcn_mfma_f32_32x32x16_bf16(vf[1], pa1, acc0, 0, 0, 0);
    acc1 = __builtin_amdgcn_mfma_f32_32x32x16_bf16(vf[2], pa0, acc1, 0, 0, 0);
    acc1 = __builtin_amdgcn_mfma_f32_32x32x16_bf16(vf[3], pa1, acc1, 0, 0, 0);

    if (c < qtile) {
#pragma unroll
      for (int dc = 0; dc < 4; dc++) kf[dc] = kfn[dc];
    }
  }

  // --- normalize + transpose via LDS, coalesced store ---
  const float rinv = 1.0f / lsum;
#pragma unroll
  for (int reg = 0; reg < 16; reg++) {
    const int d = (reg & 3) + 8 * (reg >> 2) + 4 * hi;
    olds[r][d]      = f2bf(acc0[reg] * rinv);
    olds[r][32 + d] = f2bf(acc1[reg] * rinv);
  }
  __syncthreads();
#pragma unroll
  for (int it = 0; it < 4; it++) {
    const int idx = it * 64 + l;
    const int row = idx >> 3;
    const int col = (idx & 7) * 8;
    short8 v = *(const short8*)&olds[row][col];
    *(short8*)(O + (size_t)(q0 + row) * DMODEL + h * 64 + col) = v;
  }
}

// ---------------------------------------------------------------------------
// launch
// ---------------------------------------------------------------------------
extern "C" void kernel_launch(void* const* d_in, const int* in_sizes, int n_in,
                              void* d_out, int out_size, void* d_ws, size_t ws_size,
                              hipStream_t stream) {
  (void)in_sizes; (void)n_in; (void)out_size; (void)ws_size;
  const float* x    = (const float*)d_in[0];   // [4096,1024]
  const float* Wqkv = (const float*)d_in[1];   // [3072,1024]
  const float* Wo   = (const float*)d_in[2];   // [1024,1024]
  float* out = (float*)d_out;                  // [4096,1024]

  char* ws = (char*)d_ws;
  const size_t MB = 1u << 20;
  unsigned short* x_bf    = (unsigned short*)(ws + 0 * MB);
  unsigned short* wqkv_bf = (unsigned short*)(ws + 8 * MB);
  unsigned short* wo_bf   = (unsigned short*)(ws + 14 * MB);
  unsigned short* qkv_bf  = (unsigned short*)(ws + 16 * MB);
  unsigned short* Qr      = (unsigned short*)(ws + 40 * MB);
  unsigned short* Kr      = (unsigned short*)(ws + 48 * MB);
  unsigned short* Vt      = (unsigned short*)(ws + 56 * MB);
  unsigned short* Obf     = (unsigned short*)(ws + 64 * MB);

  const int n_x = 4096 * 1024, n_wqkv = 3072 * 1024, n_wo = 1024 * 1024;
  cvt_bf16_kernel<<<(n_x / 4 + 255) / 256, 256, 0, stream>>>(x, x_bf, n_x / 4);
  cvt_bf16_kernel<<<(n_wqkv / 4 + 255) / 256, 256, 0, stream>>>(Wqkv, wqkv_bf, n_wqkv / 4);
  cvt_bf16_kernel<<<(n_wo / 4 + 255) / 256, 256, 0, stream>>>(Wo, wo_bf, n_wo / 4);

  gemm_bt<true><<<dim3(3072 / 128, 4096 / 64), 256, 0, stream>>>(x_bf, wqkv_bf, qkv_bf,
                                                                 4096, 3072, 1024);
  rope_split_kernel<<<(4096 * 1024) / 256, 256, 0, stream>>>(qkv_bf, Qr, Kr, Vt);

  flash_attn_kernel<<<2048, 64, 0, stream>>>(Qr, Kr, Vt, Obf);

  gemm_bt<false><<<dim3(1024 / 128, 4096 / 64), 256, 0, stream>>>(Obf, wo_bf, out,
                                                                  4096, 1024, 1024);
}

// Round 4
// 246.169 us; speedup vs baseline: 2.7860x; 1.5410x over previous
//
#include <hip/hip_runtime.h>

// ---------------------------------------------------------------------------
// CausalSelfAttention fused block, MI355X (gfx950)
// Round 3: m97-structure LDS GEMM (128x128 tile, global_load_lds width-16,
// 2-barrier K-loop) for both GEMMs. Flash attention unchanged from round 2.
// ---------------------------------------------------------------------------

typedef __attribute__((ext_vector_type(8)))  short  short8;
typedef __attribute__((ext_vector_type(4)))  float  f32x4;
typedef __attribute__((ext_vector_type(16))) float  f32x16;
typedef __attribute__((ext_vector_type(4)))  float  float4v;
typedef __attribute__((ext_vector_type(4)))  unsigned short ushort4v;
typedef __attribute__((ext_vector_type(4)))  unsigned int   uint4v;

#define S_LEN 4096
#define DMODEL 1024
#define NHEADS 16
#define DKH 64

// 0.125 * log2(e): folds 1/sqrt(64) and the exp->exp2 conversion into Q.
#define QSCALE 0.18033688011112042f

__device__ __forceinline__ unsigned short f2bf(float f) {
  unsigned u = __builtin_bit_cast(unsigned, f);
  u += 0x7FFFu + ((u >> 16) & 1u);   // round-to-nearest-even
  return (unsigned short)(u >> 16);
}
__device__ __forceinline__ float bf2f(unsigned short h) {
  return __builtin_bit_cast(float, ((unsigned)h) << 16);
}

// async global->LDS, 16B per lane. LDS dest must be linear (uniform base +
// lane*16): our segment numbering guarantees exactly that.
#define GLDS16(gsrc, ldst)                                                   \
  __builtin_amdgcn_global_load_lds(                                          \
      (const __attribute__((address_space(1))) void*)(gsrc),                 \
      (__attribute__((address_space(3))) void*)(ldst), 16, 0, 0)

// ---------------------------------------------------------------------------
// fp32 -> bf16 conversion
// ---------------------------------------------------------------------------
__global__ void cvt_bf16_kernel(const float* __restrict__ src,
                                unsigned short* __restrict__ dst, int n4) {
  int i = blockIdx.x * blockDim.x + threadIdx.x;
  if (i >= n4) return;
  float4v v = reinterpret_cast<const float4v*>(src)[i];
  ushort4v o;
  o[0] = f2bf(v[0]); o[1] = f2bf(v[1]); o[2] = f2bf(v[2]); o[3] = f2bf(v[3]);
  reinterpret_cast<ushort4v*>(dst)[i] = o;
}

// ---------------------------------------------------------------------------
// m97-structure GEMM: C[M,N] = A[M,K] * B[N,K]^T, bf16 in, f32 accum.
// Block 256 thr = 4 waves (2x2). Tile 128x128, BK=32. LDS 16 KB single-buffer.
// Staging: 512 16B-segments per tile, segment s -> row s>>2, kcol (s&3)*8;
// thread t stages s = t and s = t+256 (LDS dest = base + lane*16, linear).
// ---------------------------------------------------------------------------
template<bool OUT_BF16>
__global__ __launch_bounds__(256) void gemm_lds(const unsigned short* __restrict__ A,
                                                const unsigned short* __restrict__ B,
                                                void* __restrict__ Cp,
                                                int M, int N, int K) {
  __shared__ __align__(16) unsigned short As[128 * 32];
  __shared__ __align__(16) unsigned short Bs[128 * 32];

  const int tid = threadIdx.x;
  const int l = tid & 63, w = tid >> 6;
  const int wr = w >> 1, wc = w & 1;
  const int bm = blockIdx.y * 128, bn = blockIdx.x * 128;
  const int lr = l & 15, lk = (l >> 4) * 8;

  f32x4 acc[4][4] = {};

  // staging source/dest (segment tid and tid+256)
  const unsigned short* Ag0 = A + (size_t)(bm + (tid >> 2)) * K + (tid & 3) * 8;
  const unsigned short* Ag1 = A + (size_t)(bm + 64 + (tid >> 2)) * K + (tid & 3) * 8;
  const unsigned short* Bg0 = B + (size_t)(bn + (tid >> 2)) * K + (tid & 3) * 8;
  const unsigned short* Bg1 = B + (size_t)(bn + 64 + (tid >> 2)) * K + (tid & 3) * 8;
  unsigned short* Ad0 = As + tid * 8;
  unsigned short* Ad1 = As + (tid + 256) * 8;
  unsigned short* Bd0 = Bs + tid * 8;
  unsigned short* Bd1 = Bs + (tid + 256) * 8;

  // fragment read pointers
  const unsigned short* Afr = As + (wr * 64 + lr) * 32 + lk;
  const unsigned short* Bfr = Bs + (wc * 64 + lr) * 32 + lk;

  for (int k0 = 0; k0 < K; k0 += 32) {
    GLDS16(Ag0 + k0, Ad0);
    GLDS16(Ag1 + k0, Ad1);
    GLDS16(Bg0 + k0, Bd0);
    GLDS16(Bg1 + k0, Bd1);
    __syncthreads();   // compiler emits vmcnt(0) drain before barrier

    short8 af[4], bfr[4];
#pragma unroll
    for (int mi = 0; mi < 4; mi++) af[mi]  = *(const short8*)(Afr + mi * 16 * 32);
#pragma unroll
    for (int ni = 0; ni < 4; ni++) bfr[ni] = *(const short8*)(Bfr + ni * 16 * 32);

#pragma unroll
    for (int mi = 0; mi < 4; mi++)
#pragma unroll
      for (int ni = 0; ni < 4; ni++)
        acc[mi][ni] = __builtin_amdgcn_mfma_f32_16x16x32_bf16(af[mi], bfr[ni],
                                                              acc[mi][ni], 0, 0, 0);
    __syncthreads();   // protect LDS from next iteration's overwrite
  }

  const int row0 = bm + wr * 64 + (l >> 4) * 4;
  const int col0 = bn + wc * 64 + lr;
#pragma unroll
  for (int mi = 0; mi < 4; mi++)
#pragma unroll
    for (int ni = 0; ni < 4; ni++)
#pragma unroll
      for (int j = 0; j < 4; j++) {
        size_t idx = (size_t)(row0 + mi * 16 + j) * N + (col0 + ni * 16);
        if (OUT_BF16) ((unsigned short*)Cp)[idx] = f2bf(acc[mi][ni][j]);
        else          ((float*)Cp)[idx]          = acc[mi][ni][j];
      }
}

// ---------------------------------------------------------------------------
// RoPE + head reshape. Q pre-scaled by 0.125*log2e. V transposed to [H][64][S].
// ---------------------------------------------------------------------------
__global__ void rope_split_kernel(const unsigned short* __restrict__ qkv,
                                  unsigned short* __restrict__ Qr,
                                  unsigned short* __restrict__ Kr,
                                  unsigned short* __restrict__ Vt) {
  int gid = blockIdx.x * blockDim.x + threadIdx.x;  // 0 .. 4M-1
  int s = gid >> 10;
  int e = gid & 1023;
  int h = e >> 6, d = e & 63;
  size_t base = (size_t)s * 3072;

  float q = bf2f(qkv[base + e]);
  float k = bf2f(qkv[base + 1024 + e]);

  int i = d & 31;
  float inv = expf(-(float)(2 * i) * (9.2103403719761836f / 64.0f));
  float ang = (float)s * inv;
  float sn, cs;
  sincosf(ang, &sn, &cs);

  int ep = (d < 32) ? (e + 32) : (e - 32);
  float qp = bf2f(qkv[base + ep]);
  float kp = bf2f(qkv[base + 1024 + ep]);

  float qo, ko;
  if (d < 32) { qo = q * cs - qp * sn; ko = k * cs - kp * sn; }
  else        { qo = q * cs + qp * sn; ko = k * cs + kp * sn; }

  size_t oidx = ((size_t)h * S_LEN + s) * DKH + d;
  Qr[oidx] = f2bf(qo * QSCALE);
  Kr[oidx] = f2bf(ko);
  Vt[((size_t)h * DKH + d) * S_LEN + s] = qkv[base + 2048 + e];
}

// ---------------------------------------------------------------------------
// Flash attention, swapped-QK^T 32x32x16 structure (unchanged from round 2).
// ---------------------------------------------------------------------------
__global__ __launch_bounds__(64) void flash_attn_kernel(const unsigned short* __restrict__ Qr,
                                                        const unsigned short* __restrict__ Kr,
                                                        const unsigned short* __restrict__ Vt,
                                                        unsigned short* __restrict__ O) {
  __shared__ __align__(16) unsigned short olds[32][72];

  const int l  = threadIdx.x;
  const int r  = l & 31;
  const int hi = l >> 5;

  const int bx    = blockIdx.x;          // 0..2047
  const int xcd   = bx & 7;
  const int j     = bx >> 3;             // 0..255
  const int h     = xcd * 2 + (j & 1);   // 2 heads per XCD
  const int qtile = 127 - (j >> 1);      // longest first
  const int q0    = qtile * 32;

  const unsigned short* Qh = Qr + (size_t)h * S_LEN * DKH;
  const unsigned short* Kh = Kr + (size_t)h * S_LEN * DKH;
  const unsigned short* Vh = Vt + (size_t)h * DKH * S_LEN;

  short8 qf[4];
  {
    const unsigned short* qb = Qh + (size_t)(q0 + r) * 64 + hi * 8;
#pragma unroll
    for (int dc = 0; dc < 4; dc++) qf[dc] = *(const short8*)(qb + dc * 16);
  }

  f32x16 acc0 = {}, acc1 = {};     // O^T tiles: d 0..31 / 32..63, col=q
  float m = -1e30f, lsum = 0.0f;

  short8 kf[4];
  {
    const unsigned short* kb = Kh + (size_t)r * 64 + hi * 8;
#pragma unroll
    for (int dc = 0; dc < 4; dc++) kf[dc] = *(const short8*)(kb + dc * 16);
  }

  for (int c = 0; c <= qtile; c++) {
    const int kv0 = c << 5;

    short8 vf[4];
    {
      const unsigned short* vb = Vh + (size_t)r * S_LEN + kv0 + hi * 8;
#pragma unroll
      for (int dt = 0; dt < 2; dt++)
#pragma unroll
        for (int kc = 0; kc < 2; kc++)
          vf[dt * 2 + kc] = *(const short8*)(vb + (size_t)dt * 32 * S_LEN + kc * 16);
    }

    f32x16 st = {};
    st = __builtin_amdgcn_mfma_f32_32x32x16_bf16(kf[0], qf[0], st, 0, 0, 0);
    st = __builtin_amdgcn_mfma_f32_32x32x16_bf16(kf[1], qf[1], st, 0, 0, 0);
    st = __builtin_amdgcn_mfma_f32_32x32x16_bf16(kf[2], qf[2], st, 0, 0, 0);
    st = __builtin_amdgcn_mfma_f32_32x32x16_bf16(kf[3], qf[3], st, 0, 0, 0);

    short8 kfn[4];
    if (c < qtile) {
      const unsigned short* kb = Kh + (size_t)(kv0 + 32 + r) * 64 + hi * 8;
#pragma unroll
      for (int dc = 0; dc < 4; dc++) kfn[dc] = *(const short8*)(kb + dc * 16);
    }

    if (c == qtile) {
#pragma unroll
      for (int reg = 0; reg < 16; reg++) {
        const int koff = (reg & 3) + 8 * (reg >> 2) + 4 * hi;
        if (koff > r) st[reg] = -1e30f;
      }
    }

    float t[8];
#pragma unroll
    for (int i = 0; i < 8; i++) t[i] = fmaxf(st[2 * i], st[2 * i + 1]);
#pragma unroll
    for (int i = 0; i < 4; i++) t[i] = fmaxf(t[i], t[i + 4]);
    float pm = fmaxf(fmaxf(t[0], t[2]), fmaxf(t[1], t[3]));
    pm = fmaxf(pm, __shfl_xor(pm, 32));

    if (!__all(pm <= m + 8.0f)) {
      float mn  = fmaxf(m, pm);
      float scl = exp2f(m - mn);
      m = mn;
      lsum *= scl;
#pragma unroll
      for (int reg = 0; reg < 16; reg++) { acc0[reg] *= scl; acc1[reg] *= scl; }
    }

    float p[16];
#pragma unroll
    for (int reg = 0; reg < 16; reg++) p[reg] = exp2f(st[reg] - m);

    float s2[8];
#pragma unroll
    for (int i = 0; i < 8; i++) s2[i] = p[2 * i] + p[2 * i + 1];
#pragma unroll
    for (int i = 0; i < 4; i++) s2[i] = s2[i] + s2[i + 4];
    float rs = (s2[0] + s2[2]) + (s2[1] + s2[3]);
    rs += __shfl_xor(rs, 32);
    lsum += rs;

    unsigned wd[8];
#pragma unroll
    for (int i = 0; i < 8; i++) {
      asm("v_cvt_pk_bf16_f32 %0, %1, %2" : "=v"(wd[i]) : "v"(p[2 * i]), "v"(p[2 * i + 1]));
    }
    unsigned pw[8];
#pragma unroll
    for (int i = 0; i < 8; i++) pw[i] = __shfl_xor(wd[i], 32);

    uint4v u0, u1;
    u0[0] = hi ? pw[2] : wd[0];
    u0[1] = hi ? pw[3] : wd[1];
    u0[2] = hi ? wd[2] : pw[0];
    u0[3] = hi ? wd[3] : pw[1];
    u1[0] = hi ? pw[6] : wd[4];
    u1[1] = hi ? pw[7] : wd[5];
    u1[2] = hi ? wd[6] : pw[4];
    u1[3] = hi ? wd[7] : pw[5];
    short8 pa0 = __builtin_bit_cast(short8, u0);   // keys kv0+0..15
    short8 pa1 = __builtin_bit_cast(short8, u1);   // keys kv0+16..31

    acc0 = __builtin_amdgcn_mfma_f32_32x32x16_bf16(vf[0], pa0, acc0, 0, 0, 0);
    acc0 = __builtin_amdgcn_mfma_f32_32x32x16_bf16(vf[1], pa1, acc0, 0, 0, 0);
    acc1 = __builtin_amdgcn_mfma_f32_32x32x16_bf16(vf[2], pa0, acc1, 0, 0, 0);
    acc1 = __builtin_amdgcn_mfma_f32_32x32x16_bf16(vf[3], pa1, acc1, 0, 0, 0);

    if (c < qtile) {
#pragma unroll
      for (int dc = 0; dc < 4; dc++) kf[dc] = kfn[dc];
    }
  }

  const float rinv = 1.0f / lsum;
#pragma unroll
  for (int reg = 0; reg < 16; reg++) {
    const int d = (reg & 3) + 8 * (reg >> 2) + 4 * hi;
    olds[r][d]      = f2bf(acc0[reg] * rinv);
    olds[r][32 + d] = f2bf(acc1[reg] * rinv);
  }
  __syncthreads();
#pragma unroll
  for (int it = 0; it < 4; it++) {
    const int idx = it * 64 + l;
    const int row = idx >> 3;
    const int col = (idx & 7) * 8;
    short8 v = *(const short8*)&olds[row][col];
    *(short8*)(O + (size_t)(q0 + row) * DMODEL + h * 64 + col) = v;
  }
}

// ---------------------------------------------------------------------------
// launch
// ---------------------------------------------------------------------------
extern "C" void kernel_launch(void* const* d_in, const int* in_sizes, int n_in,
                              void* d_out, int out_size, void* d_ws, size_t ws_size,
                              hipStream_t stream) {
  (void)in_sizes; (void)n_in; (void)out_size; (void)ws_size;
  const float* x    = (const float*)d_in[0];   // [4096,1024]
  const float* Wqkv = (const float*)d_in[1];   // [3072,1024]
  const float* Wo   = (const float*)d_in[2];   // [1024,1024]
  float* out = (float*)d_out;                  // [4096,1024]

  char* ws = (char*)d_ws;
  const size_t MB = 1u << 20;
  unsigned short* x_bf    = (unsigned short*)(ws + 0 * MB);
  unsigned short* wqkv_bf = (unsigned short*)(ws + 8 * MB);
  unsigned short* wo_bf   = (unsigned short*)(ws + 14 * MB);
  unsigned short* qkv_bf  = (unsigned short*)(ws + 16 * MB);
  unsigned short* Qr      = (unsigned short*)(ws + 40 * MB);
  unsigned short* Kr      = (unsigned short*)(ws + 48 * MB);
  unsigned short* Vt      = (unsigned short*)(ws + 56 * MB);
  unsigned short* Obf     = (unsigned short*)(ws + 64 * MB);

  const int n_x = 4096 * 1024, n_wqkv = 3072 * 1024, n_wo = 1024 * 1024;
  cvt_bf16_kernel<<<(n_x / 4 + 255) / 256, 256, 0, stream>>>(x, x_bf, n_x / 4);
  cvt_bf16_kernel<<<(n_wqkv / 4 + 255) / 256, 256, 0, stream>>>(Wqkv, wqkv_bf, n_wqkv / 4);
  cvt_bf16_kernel<<<(n_wo / 4 + 255) / 256, 256, 0, stream>>>(Wo, wo_bf, n_wo / 4);

  // qkv = x . Wqkv^T : M=4096, N=3072, K=1024
  gemm_lds<true><<<dim3(3072 / 128, 4096 / 128), 256, 0, stream>>>(x_bf, wqkv_bf, qkv_bf,
                                                                   4096, 3072, 1024);
  rope_split_kernel<<<(4096 * 1024) / 256, 256, 0, stream>>>(qkv_bf, Qr, Kr, Vt);

  flash_attn_kernel<<<2048, 64, 0, stream>>>(Qr, Kr, Vt, Obf);

  // out = O . Wo^T : M=4096, N=1024, K=1024
  gemm_lds<false><<<dim3(1024 / 128, 4096 / 128), 256, 0, stream>>>(Obf, wo_bf, out,
                                                                    4096, 1024, 1024);
}

// Round 5
// 227.706 us; speedup vs baseline: 3.0119x; 1.0811x over previous
//
#include <hip/hip_runtime.h>

// ---------------------------------------------------------------------------
// CausalSelfAttention fused block, MI355X (gfx950)
// Round 4: flash attention gets 4-wave intra-block KV-split (wave w handles
// chunks w, w+4, ...) + LSE combine through LDS. GEMMs (m97 LDS structure),
// rope, cvt unchanged from round 3.
// ---------------------------------------------------------------------------

typedef __attribute__((ext_vector_type(8)))  short  short8;
typedef __attribute__((ext_vector_type(4)))  float  f32x4;
typedef __attribute__((ext_vector_type(16))) float  f32x16;
typedef __attribute__((ext_vector_type(4)))  float  float4v;
typedef __attribute__((ext_vector_type(4)))  unsigned short ushort4v;
typedef __attribute__((ext_vector_type(4)))  unsigned int   uint4v;

#define S_LEN 4096
#define DMODEL 1024
#define NHEADS 16
#define DKH 64

// 0.125 * log2(e): folds 1/sqrt(64) and the exp->exp2 conversion into Q.
#define QSCALE 0.18033688011112042f

__device__ __forceinline__ unsigned short f2bf(float f) {
  unsigned u = __builtin_bit_cast(unsigned, f);
  u += 0x7FFFu + ((u >> 16) & 1u);   // round-to-nearest-even
  return (unsigned short)(u >> 16);
}
__device__ __forceinline__ float bf2f(unsigned short h) {
  return __builtin_bit_cast(float, ((unsigned)h) << 16);
}

// async global->LDS, 16B per lane (linear dest: uniform base + lane*16).
#define GLDS16(gsrc, ldst)                                                   \
  __builtin_amdgcn_global_load_lds(                                          \
      (const __attribute__((address_space(1))) void*)(gsrc),                 \
      (__attribute__((address_space(3))) void*)(ldst), 16, 0, 0)

// ---------------------------------------------------------------------------
// fp32 -> bf16 conversion
// ---------------------------------------------------------------------------
__global__ void cvt_bf16_kernel(const float* __restrict__ src,
                                unsigned short* __restrict__ dst, int n4) {
  int i = blockIdx.x * blockDim.x + threadIdx.x;
  if (i >= n4) return;
  float4v v = reinterpret_cast<const float4v*>(src)[i];
  ushort4v o;
  o[0] = f2bf(v[0]); o[1] = f2bf(v[1]); o[2] = f2bf(v[2]); o[3] = f2bf(v[3]);
  reinterpret_cast<ushort4v*>(dst)[i] = o;
}

// ---------------------------------------------------------------------------
// m97-structure GEMM: C[M,N] = A[M,K] * B[N,K]^T, bf16 in, f32 accum.
// ---------------------------------------------------------------------------
template<bool OUT_BF16>
__global__ __launch_bounds__(256) void gemm_lds(const unsigned short* __restrict__ A,
                                                const unsigned short* __restrict__ B,
                                                void* __restrict__ Cp,
                                                int M, int N, int K) {
  __shared__ __align__(16) unsigned short As[128 * 32];
  __shared__ __align__(16) unsigned short Bs[128 * 32];

  const int tid = threadIdx.x;
  const int l = tid & 63, w = tid >> 6;
  const int wr = w >> 1, wc = w & 1;
  const int bm = blockIdx.y * 128, bn = blockIdx.x * 128;
  const int lr = l & 15, lk = (l >> 4) * 8;

  f32x4 acc[4][4] = {};

  const unsigned short* Ag0 = A + (size_t)(bm + (tid >> 2)) * K + (tid & 3) * 8;
  const unsigned short* Ag1 = A + (size_t)(bm + 64 + (tid >> 2)) * K + (tid & 3) * 8;
  const unsigned short* Bg0 = B + (size_t)(bn + (tid >> 2)) * K + (tid & 3) * 8;
  const unsigned short* Bg1 = B + (size_t)(bn + 64 + (tid >> 2)) * K + (tid & 3) * 8;
  unsigned short* Ad0 = As + tid * 8;
  unsigned short* Ad1 = As + (tid + 256) * 8;
  unsigned short* Bd0 = Bs + tid * 8;
  unsigned short* Bd1 = Bs + (tid + 256) * 8;

  const unsigned short* Afr = As + (wr * 64 + lr) * 32 + lk;
  const unsigned short* Bfr = Bs + (wc * 64 + lr) * 32 + lk;

  for (int k0 = 0; k0 < K; k0 += 32) {
    GLDS16(Ag0 + k0, Ad0);
    GLDS16(Ag1 + k0, Ad1);
    GLDS16(Bg0 + k0, Bd0);
    GLDS16(Bg1 + k0, Bd1);
    __syncthreads();

    short8 af[4], bfr[4];
#pragma unroll
    for (int mi = 0; mi < 4; mi++) af[mi]  = *(const short8*)(Afr + mi * 16 * 32);
#pragma unroll
    for (int ni = 0; ni < 4; ni++) bfr[ni] = *(const short8*)(Bfr + ni * 16 * 32);

#pragma unroll
    for (int mi = 0; mi < 4; mi++)
#pragma unroll
      for (int ni = 0; ni < 4; ni++)
        acc[mi][ni] = __builtin_amdgcn_mfma_f32_16x16x32_bf16(af[mi], bfr[ni],
                                                              acc[mi][ni], 0, 0, 0);
    __syncthreads();
  }

  const int row0 = bm + wr * 64 + (l >> 4) * 4;
  const int col0 = bn + wc * 64 + lr;
#pragma unroll
  for (int mi = 0; mi < 4; mi++)
#pragma unroll
    for (int ni = 0; ni < 4; ni++)
#pragma unroll
      for (int j = 0; j < 4; j++) {
        size_t idx = (size_t)(row0 + mi * 16 + j) * N + (col0 + ni * 16);
        if (OUT_BF16) ((unsigned short*)Cp)[idx] = f2bf(acc[mi][ni][j]);
        else          ((float*)Cp)[idx]          = acc[mi][ni][j];
      }
}

// ---------------------------------------------------------------------------
// RoPE + head reshape. Q pre-scaled by 0.125*log2e. V transposed to [H][64][S].
// ---------------------------------------------------------------------------
__global__ void rope_split_kernel(const unsigned short* __restrict__ qkv,
                                  unsigned short* __restrict__ Qr,
                                  unsigned short* __restrict__ Kr,
                                  unsigned short* __restrict__ Vt) {
  int gid = blockIdx.x * blockDim.x + threadIdx.x;  // 0 .. 4M-1
  int s = gid >> 10;
  int e = gid & 1023;
  int h = e >> 6, d = e & 63;
  size_t base = (size_t)s * 3072;

  float q = bf2f(qkv[base + e]);
  float k = bf2f(qkv[base + 1024 + e]);

  int i = d & 31;
  float inv = expf(-(float)(2 * i) * (9.2103403719761836f / 64.0f));
  float ang = (float)s * inv;
  float sn, cs;
  sincosf(ang, &sn, &cs);

  int ep = (d < 32) ? (e + 32) : (e - 32);
  float qp = bf2f(qkv[base + ep]);
  float kp = bf2f(qkv[base + 1024 + ep]);

  float qo, ko;
  if (d < 32) { qo = q * cs - qp * sn; ko = k * cs - kp * sn; }
  else        { qo = q * cs + qp * sn; ko = k * cs + kp * sn; }

  size_t oidx = ((size_t)h * S_LEN + s) * DKH + d;
  Qr[oidx] = f2bf(qo * QSCALE);
  Kr[oidx] = f2bf(ko);
  Vt[((size_t)h * DKH + d) * S_LEN + s] = qkv[base + 2048 + e];
}

// ---------------------------------------------------------------------------
// Flash attention, swapped-QK^T 32x32x16, 4-wave KV-split.
// Wave w handles chunks c = w, w+4, ... of (head, qtile); per-wave online
// softmax; LSE combine via LDS at the end.
// ---------------------------------------------------------------------------
__global__ __launch_bounds__(256) void flash_attn_kernel(const unsigned short* __restrict__ Qr,
                                                         const unsigned short* __restrict__ Kr,
                                                         const unsigned short* __restrict__ Vt,
                                                         unsigned short* __restrict__ O) {
  __shared__ float oacc[4][32][65];   // [wave][q][d], pad 65 -> conflict-free
  __shared__ float ml_m[4][32];
  __shared__ float ml_l[4][32];

  const int tid = threadIdx.x;
  const int l  = tid & 63;
  const int w  = tid >> 6;            // wave 0..3
  const int r  = l & 31;
  const int hi = l >> 5;

  // XCD-pinned head mapping + longest-tile-first dispatch.
  const int bx    = blockIdx.x;          // 0..2047
  const int xcd   = bx & 7;
  const int j     = bx >> 3;             // 0..255
  const int h     = xcd * 2 + (j & 1);   // 2 heads per XCD -> K/V L2-resident
  const int qtile = 127 - (j >> 1);      // longest first
  const int q0    = qtile * 32;

  const unsigned short* Qh = Qr + (size_t)h * S_LEN * DKH;
  const unsigned short* Kh = Kr + (size_t)h * S_LEN * DKH;
  const unsigned short* Vh = Vt + (size_t)h * DKH * S_LEN;

  // Q B-fragments (col=q, k=d-chunk), pre-scaled by QSCALE in rope.
  short8 qf[4];
  {
    const unsigned short* qb = Qh + (size_t)(q0 + r) * 64 + hi * 8;
#pragma unroll
    for (int dc = 0; dc < 4; dc++) qf[dc] = *(const short8*)(qb + dc * 16);
  }

  f32x16 acc0 = {}, acc1 = {};     // O^T tiles: d 0..31 / 32..63, col=q
  float m = -1e30f, lsum = 0.0f;

  // preload this wave's first K chunk (rows w*32 + r -- always in range)
  short8 kf[4];
  {
    const unsigned short* kb = Kh + (size_t)(w * 32 + r) * 64 + hi * 8;
#pragma unroll
    for (int dc = 0; dc < 4; dc++) kf[dc] = *(const short8*)(kb + dc * 16);
  }

  for (int c = w; c <= qtile; c += 4) {
    const int kv0 = c << 5;

    // V A-frags issued early: row=d, k=key
    short8 vf[4];
    {
      const unsigned short* vb = Vh + (size_t)r * S_LEN + kv0 + hi * 8;
#pragma unroll
      for (int dt = 0; dt < 2; dt++)
#pragma unroll
        for (int kc = 0; kc < 2; kc++)
          vf[dt * 2 + kc] = *(const short8*)(vb + (size_t)dt * 32 * S_LEN + kc * 16);
    }

    // S^T = K . Q^T
    f32x16 st = {};
    st = __builtin_amdgcn_mfma_f32_32x32x16_bf16(kf[0], qf[0], st, 0, 0, 0);
    st = __builtin_amdgcn_mfma_f32_32x32x16_bf16(kf[1], qf[1], st, 0, 0, 0);
    st = __builtin_amdgcn_mfma_f32_32x32x16_bf16(kf[2], qf[2], st, 0, 0, 0);
    st = __builtin_amdgcn_mfma_f32_32x32x16_bf16(kf[3], qf[3], st, 0, 0, 0);

    // prefetch this wave's next K chunk under the softmax
    short8 kfn[4];
    if (c + 4 <= qtile) {
      const unsigned short* kb = Kh + (size_t)((c + 4) * 32 + r) * 64 + hi * 8;
#pragma unroll
      for (int dc = 0; dc < 4; dc++) kfn[dc] = *(const short8*)(kb + dc * 16);
    }

    // causal mask: only the diagonal chunk (owned by wave qtile%4)
    if (c == qtile) {
#pragma unroll
      for (int reg = 0; reg < 16; reg++) {
        const int koff = (reg & 3) + 8 * (reg >> 2) + 4 * hi;
        if (koff > r) st[reg] = -1e30f;
      }
    }

    // --- lane-local online softmax (exp2 domain) ---
    float t[8];
#pragma unroll
    for (int i = 0; i < 8; i++) t[i] = fmaxf(st[2 * i], st[2 * i + 1]);
#pragma unroll
    for (int i = 0; i < 4; i++) t[i] = fmaxf(t[i], t[i + 4]);
    float pm = fmaxf(fmaxf(t[0], t[2]), fmaxf(t[1], t[3]));
    pm = fmaxf(pm, __shfl_xor(pm, 32));

    if (!__all(pm <= m + 8.0f)) {
      float mn  = fmaxf(m, pm);
      float scl = exp2f(m - mn);
      m = mn;
      lsum *= scl;
#pragma unroll
      for (int reg = 0; reg < 16; reg++) { acc0[reg] *= scl; acc1[reg] *= scl; }
    }

    float p[16];
#pragma unroll
    for (int reg = 0; reg < 16; reg++) p[reg] = exp2f(st[reg] - m);

    float s2[8];
#pragma unroll
    for (int i = 0; i < 8; i++) s2[i] = p[2 * i] + p[2 * i + 1];
#pragma unroll
    for (int i = 0; i < 4; i++) s2[i] = s2[i] + s2[i + 4];
    float rs = (s2[0] + s2[2]) + (s2[1] + s2[3]);
    rs += __shfl_xor(rs, 32);
    lsum += rs;

    // --- pack P to bf16 words and build PV B-fragments ---
    unsigned wd[8];
#pragma unroll
    for (int i = 0; i < 8; i++) {
      asm("v_cvt_pk_bf16_f32 %0, %1, %2" : "=v"(wd[i]) : "v"(p[2 * i]), "v"(p[2 * i + 1]));
    }
    unsigned pw[8];
#pragma unroll
    for (int i = 0; i < 8; i++) pw[i] = __shfl_xor(wd[i], 32);

    uint4v u0, u1;
    u0[0] = hi ? pw[2] : wd[0];
    u0[1] = hi ? pw[3] : wd[1];
    u0[2] = hi ? wd[2] : pw[0];
    u0[3] = hi ? wd[3] : pw[1];
    u1[0] = hi ? pw[6] : wd[4];
    u1[1] = hi ? pw[7] : wd[5];
    u1[2] = hi ? wd[6] : pw[4];
    u1[3] = hi ? wd[7] : pw[5];
    short8 pa0 = __builtin_bit_cast(short8, u0);   // keys kv0+0..15
    short8 pa1 = __builtin_bit_cast(short8, u1);   // keys kv0+16..31

    // O^T += V^T . P
    acc0 = __builtin_amdgcn_mfma_f32_32x32x16_bf16(vf[0], pa0, acc0, 0, 0, 0);
    acc0 = __builtin_amdgcn_mfma_f32_32x32x16_bf16(vf[1], pa1, acc0, 0, 0, 0);
    acc1 = __builtin_amdgcn_mfma_f32_32x32x16_bf16(vf[2], pa0, acc1, 0, 0, 0);
    acc1 = __builtin_amdgcn_mfma_f32_32x32x16_bf16(vf[3], pa1, acc1, 0, 0, 0);

    if (c + 4 <= qtile) {
#pragma unroll
      for (int dc = 0; dc < 4; dc++) kf[dc] = kfn[dc];
    }
  }

  // --- LSE combine of the 4 per-wave partials ---
  if (hi == 0) { ml_m[w][r] = m; ml_l[w][r] = lsum; }
#pragma unroll
  for (int reg = 0; reg < 16; reg++) {
    const int d = (reg & 3) + 8 * (reg >> 2) + 4 * hi;
    oacc[w][r][d]      = acc0[reg];
    oacc[w][r][32 + d] = acc1[reg];
  }
  __syncthreads();

  const int q  = tid >> 3;          // 0..31
  const int d0 = (tid & 7) * 8;     // 0..56
  const float m0 = ml_m[0][q], m1 = ml_m[1][q], m2 = ml_m[2][q], m3 = ml_m[3][q];
  const float mmax = fmaxf(fmaxf(m0, m1), fmaxf(m2, m3));
  const float sc0 = exp2f(m0 - mmax), sc1 = exp2f(m1 - mmax);
  const float sc2 = exp2f(m2 - mmax), sc3 = exp2f(m3 - mmax);
  const float ltot = sc0 * ml_l[0][q] + sc1 * ml_l[1][q] +
                     sc2 * ml_l[2][q] + sc3 * ml_l[3][q];
  const float rinv = 1.0f / ltot;

  ushort4v ov[2];
#pragma unroll
  for (int half = 0; half < 2; half++)
#pragma unroll
    for (int i = 0; i < 4; i++) {
      const int d = d0 + half * 4 + i;
      float v = sc0 * oacc[0][q][d] + sc1 * oacc[1][q][d] +
                sc2 * oacc[2][q][d] + sc3 * oacc[3][q][d];
      ov[half][i] = f2bf(v * rinv);
    }
  unsigned short* op = O + (size_t)(q0 + q) * DMODEL + h * 64 + d0;
  *(ushort4v*)op       = ov[0];
  *(ushort4v*)(op + 4) = ov[1];
}

// ---------------------------------------------------------------------------
// launch
// ---------------------------------------------------------------------------
extern "C" void kernel_launch(void* const* d_in, const int* in_sizes, int n_in,
                              void* d_out, int out_size, void* d_ws, size_t ws_size,
                              hipStream_t stream) {
  (void)in_sizes; (void)n_in; (void)out_size; (void)ws_size;
  const float* x    = (const float*)d_in[0];   // [4096,1024]
  const float* Wqkv = (const float*)d_in[1];   // [3072,1024]
  const float* Wo   = (const float*)d_in[2];   // [1024,1024]
  float* out = (float*)d_out;                  // [4096,1024]

  char* ws = (char*)d_ws;
  const size_t MB = 1u << 20;
  unsigned short* x_bf    = (unsigned short*)(ws + 0 * MB);
  unsigned short* wqkv_bf = (unsigned short*)(ws + 8 * MB);
  unsigned short* wo_bf   = (unsigned short*)(ws + 14 * MB);
  unsigned short* qkv_bf  = (unsigned short*)(ws + 16 * MB);
  unsigned short* Qr      = (unsigned short*)(ws + 40 * MB);
  unsigned short* Kr      = (unsigned short*)(ws + 48 * MB);
  unsigned short* Vt      = (unsigned short*)(ws + 56 * MB);
  unsigned short* Obf     = (unsigned short*)(ws + 64 * MB);

  const int n_x = 4096 * 1024, n_wqkv = 3072 * 1024, n_wo = 1024 * 1024;
  cvt_bf16_kernel<<<(n_x / 4 + 255) / 256, 256, 0, stream>>>(x, x_bf, n_x / 4);
  cvt_bf16_kernel<<<(n_wqkv / 4 + 255) / 256, 256, 0, stream>>>(Wqkv, wqkv_bf, n_wqkv / 4);
  cvt_bf16_kernel<<<(n_wo / 4 + 255) / 256, 256, 0, stream>>>(Wo, wo_bf, n_wo / 4);

  // qkv = x . Wqkv^T : M=4096, N=3072, K=1024
  gemm_lds<true><<<dim3(3072 / 128, 4096 / 128), 256, 0, stream>>>(x_bf, wqkv_bf, qkv_bf,
                                                                   4096, 3072, 1024);
  rope_split_kernel<<<(4096 * 1024) / 256, 256, 0, stream>>>(qkv_bf, Qr, Kr, Vt);

  flash_attn_kernel<<<2048, 256, 0, stream>>>(Qr, Kr, Vt, Obf);

  // out = O . Wo^T : M=4096, N=1024, K=1024
  gemm_lds<false><<<dim3(1024 / 128, 4096 / 128), 256, 0, stream>>>(Obf, wo_bf, out,
                                                                    4096, 1024, 1024);
}